// Round 8
// baseline (706.054 us; speedup 1.0000x reference)
//
#include <hip/hip_runtime.h>

#define NN 16384          // nodes
#define NE 262144         // edges
#define N64 (NN * 64)

typedef unsigned short u16;
typedef __attribute__((ext_vector_type(8))) short short8;
typedef __attribute__((ext_vector_type(4))) float f32x4;

__device__ __forceinline__ float us2f(u16 u) {
    union { unsigned int i; float f; } v; v.i = ((unsigned int)u) << 16; return v.f;
}
__device__ __forceinline__ u16 f2us(float x) {   // f32 -> bf16 bits, RNE
    union { float f; unsigned int i; } u; u.f = x;
    unsigned int r = u.i + 0x7FFF + ((u.i >> 16) & 1);
    return (u16)(r >> 16);
}
__device__ __forceinline__ float silu_f(float x) { return x / (1.0f + __expf(-x)); }
__device__ __forceinline__ float ldf(const void* p, long i, int f) {
    return f ? ((const float*)p)[i] : us2f(((const u16*)p)[i]);
}

// ---------------- dtype sniff (drives only k_convert) --------------------------
__global__ void k_sniff(const u16* __restrict__ re, int* __restrict__ flag) {
    int t = threadIdx.x;
    int hit = (re[t] >= 0x4000) ? 1 : 0;
    unsigned long long b = __ballot(hit);
    if (t == 0) *flag = (__popcll(b) >= 4) ? 1 : 0;   // 1 => f32 inputs
}

// ---------------- convert every float tensor to a bf16 ws copy ------------------
#define SB0 1048576L
#define SB1 4194304L
#define SB2 4456448L
#define SB3 5242880L
#define SB4 7340032L
#define SB5 7344128L
#define SB6 7348224L
#define SB7 7348736L
#define SB8 7365120L
#define SB9 7381504L
#define SB10 7389696L
#define SB11 7422464L
#define SB12 7438848L   // total; /256 = 29058 blocks

__global__ void k_convert(const void* x0, const void* x1, const void* ey0, const void* ey1,
                          const void* re, const void* Wup0, const void* Wup1, const void* Rw1,
                          const void* Rw2, const void* Wd0, const void* Wd1, const void* Wsc0,
                          const void* Wsc1, const int* __restrict__ flag,
                          u16* c_x0, u16* c_x1, u16* c_ey0, u16* c_ey1, u16* c_re,
                          u16* c_Wup0, u16* c_Wup1, u16* c_Rw1, u16* c_Rw2,
                          u16* c_Wd0, u16* c_Wd1, u16* c_Wsc0, u16* c_Wsc1) {
    long i = (long)blockIdx.x * 256 + threadIdx.x;
    int f = *flag;
    if (i < SB0)       { c_x0[i]          = f2us(ldf(x0, i, f)); }
    else if (i < SB1)  { c_x1[i - SB0]    = f2us(ldf(x1, i - SB0, f)); }
    else if (i < SB2)  { c_ey0[i - SB1]   = f2us(ldf(ey0, i - SB1, f)); }
    else if (i < SB3)  { c_ey1[i - SB2]   = f2us(ldf(ey1, i - SB2, f)); }
    else if (i < SB4)  { c_re[i - SB3]    = f2us(ldf(re, i - SB3, f)); }
    else if (i < SB5)  { c_Wup0[i - SB4]  = f2us(ldf(Wup0, i - SB4, f)); }
    else if (i < SB6)  { c_Wup1[i - SB5]  = f2us(ldf(Wup1, i - SB5, f)); }
    else if (i < SB7)  { c_Rw1[i - SB6]   = f2us(ldf(Rw1, i - SB6, f)); }
    else if (i < SB8)  { c_Rw2[i - SB7]   = f2us(ldf(Rw2, i - SB7, f)); }
    else if (i < SB9)  { c_Wd0[i - SB8]   = f2us(ldf(Wd0, i - SB8, f)); }
    else if (i < SB10) { c_Wd1[i - SB9]   = f2us(ldf(Wd1, i - SB9, f)); }
    else if (i < SB11) { c_Wsc0[i - SB10] = f2us(ldf(Wsc0, i - SB10, f)); }
    else               { c_Wsc1[i - SB11] = f2us(ldf(Wsc1, i - SB11, f)); }
}

// ---------------- CSR build ----------------------------------------------------
__global__ void k_hist(const int* __restrict__ recv, int* __restrict__ cnt) {
    int t = blockIdx.x * 256 + threadIdx.x;
    atomicAdd(&cnt[recv[t]], 1);
}

__global__ void k_scan(const int* __restrict__ cnt, int* __restrict__ offs,
                       int* __restrict__ cursor) {
    __shared__ int sd[256];
    int t = threadIdx.x;
    int base = t * 64;
    int sum = 0;
    for (int i = 0; i < 64; i++) sum += cnt[base + i];
    sd[t] = sum; __syncthreads();
    for (int off = 1; off < 256; off <<= 1) {
        int v = (t >= off) ? sd[t - off] : 0;
        __syncthreads();
        sd[t] += v;
        __syncthreads();
    }
    int run = sd[t] - sum;
    for (int i = 0; i < 64; i++) {
        offs[base + i] = run; cursor[base + i] = run;
        run += cnt[base + i];
    }
    if (t == 255) offs[NN] = run;
}

__global__ void k_scatter(const int* __restrict__ recv, int* __restrict__ cursor,
                          int* __restrict__ eids) {
    int t = blockIdx.x * 256 + threadIdx.x;
    int p = atomicAdd(&cursor[recv[t]], 1);
    eids[p] = t;
}

// ---------------- linear_up: h[node][64ch][4comp] interleaved bf16 --------------
__global__ void k_up_gemm(const u16* __restrict__ x0, const u16* __restrict__ x1,
                          const u16* __restrict__ Wup0, const u16* __restrict__ Wup1,
                          u16* __restrict__ h) {
    int inst = blockIdx.y;
    int wv = threadIdx.x >> 6, lane = threadIdx.x & 63;
    int lhi = lane >> 4, llo = lane & 15;
    int mb = blockIdx.x * 256 + wv * 64;
    const u16* B = (inst == 0) ? Wup0 : Wup1;

    short8 bfr[4][2];
#pragma unroll
    for (int t = 0; t < 4; t++)
#pragma unroll
        for (int s = 0; s < 2; s++)
#pragma unroll
            for (int j = 0; j < 8; j++)
                bfr[t][s][j] = (short)B[(long)(s * 32 + lhi * 8 + j) * 64 + t * 16 + llo];

    f32x4 acc[4][4];
#pragma unroll
    for (int i = 0; i < 4; i++)
#pragma unroll
        for (int t = 0; t < 4; t++) acc[i][t] = 0.0f;

#pragma unroll
    for (int s = 0; s < 2; s++) {
        short8 af[4];
#pragma unroll
        for (int i = 0; i < 4; i++) {
            int row = mb + i * 16 + llo;
            if (inst == 0) {
                af[i] = *reinterpret_cast<const short8*>(x0 + (long)row * 64 + s * 32 + lhi * 8);
            } else {
#pragma unroll
                for (int j = 0; j < 8; j++) {
                    int k = s * 32 + lhi * 8 + j;
                    af[i][j] = (short)x1[(long)row * 192 + (long)k * 3 + (inst - 1)];
                }
            }
        }
#pragma unroll
        for (int i = 0; i < 4; i++)
#pragma unroll
            for (int t = 0; t < 4; t++)
                acc[i][t] = __builtin_amdgcn_mfma_f32_16x16x32_bf16(af[i], bfr[t][s], acc[i][t], 0, 0, 0);
    }
#pragma unroll
    for (int i = 0; i < 4; i++)
#pragma unroll
        for (int t = 0; t < 4; t++)
#pragma unroll
            for (int r = 0; r < 4; r++)
                h[(long)(mb + i * 16 + lhi * 4 + r) * 256 + (t * 16 + llo) * 4 + inst] =
                    f2us(acc[i][t][r] * 0.125f);
}

// ---------------- FUSED: radial MLP + gather + linear_down + sc + gate ----------
// Block = 4 consecutive nodes (wave wv <-> node). Loops over 64-edge groups of
// the block's CSR range: stage A (hid in LDS), stage B (MFMA -> w_lds), gather
// from LDS. Radial weights never touch global memory.
#define RROW 260   // w_lds row stride in u16 (520 B, 8B-aligned rows)
__global__ void __launch_bounds__(256, 1)
k_fused(const int* __restrict__ offs, const int* __restrict__ eids,
        const int* __restrict__ senders,
        const u16* __restrict__ re, const u16* __restrict__ Rw1,
        const u16* __restrict__ Rw2, const u16* __restrict__ h,
        const u16* __restrict__ ey0, const u16* __restrict__ ey1,
        const u16* __restrict__ x0, const u16* __restrict__ x1,
        const int* __restrict__ species,
        const u16* __restrict__ Wd0, const u16* __restrict__ Wd1,
        const u16* __restrict__ Wsc0, const u16* __restrict__ Wsc1,
        float* __restrict__ out) {
    __shared__ u16 hid_s[64][72];        // 9.2 KB
    __shared__ u16 w_lds[64 * RROW];     // 33.3 KB
    __shared__ float a_lds[4][512];      // 8 KB
    int tid = threadIdx.x;
    int wv = tid >> 6, lane = tid & 63, lhi = lane >> 4, llo = lane & 15;
    int bn0 = blockIdx.x * 4;
    int node = bn0 + wv;
    int beg_blk = offs[bn0], end_blk = offs[bn0 + 4];
    int beg_w = offs[node], end_w = offs[node + 1];

    // B fragments of Rw2 for this wave's pass (pass == wv), loaded once
    short8 bfr[4][2];
#pragma unroll
    for (int t = 0; t < 4; t++)
#pragma unroll
        for (int s = 0; s < 2; s++)
#pragma unroll
            for (int j = 0; j < 8; j++)
                bfr[t][s][j] = (short)Rw2[(long)(s * 32 + lhi * 8 + j) * 256 + wv * 64 + t * 16 + llo];

    int pA = tid >> 2;                   // stage-A edge-in-group
    int jb = (tid & 3) * 16;             // stage-A col base

    float A0a = 0.f, A0b = 0.f;
    float Ax = 0.f, Ay = 0.f, Az = 0.f;
    float Bx = 0.f, By = 0.f, Bz = 0.f;

    for (int gstart = beg_blk; gstart < end_blk; gstart += 64) {
        // ---- stage A: hid = silu(re[e] @ Rw1 / sqrt(8)) for this group's 64 edges
        {
            int pos = gstart + pA;
            if (pos >= end_blk) pos = beg_blk;   // safe filler (beg_blk < end_blk here)
            int e = eids[pos];
            short8 r8 = *reinterpret_cast<const short8*>(re + (long)e * 8);
            float rr[8];
#pragma unroll
            for (int r = 0; r < 8; r++) rr[r] = us2f((u16)r8[r]);
            float hv[16];
#pragma unroll
            for (int q = 0; q < 2; q++) {
                short8 w8 = *reinterpret_cast<const short8*>(Rw1 + jb + q * 8);
#pragma unroll
                for (int j = 0; j < 8; j++) hv[q * 8 + j] = rr[0] * us2f((u16)w8[j]);
            }
#pragma unroll
            for (int r = 1; r < 8; r++) {
#pragma unroll
                for (int q = 0; q < 2; q++) {
                    short8 w8 = *reinterpret_cast<const short8*>(Rw1 + (long)r * 64 + jb + q * 8);
#pragma unroll
                    for (int j = 0; j < 8; j++) hv[q * 8 + j] += rr[r] * us2f((u16)w8[j]);
                }
            }
#pragma unroll
            for (int q = 0; q < 4; q++) {
                ushort4 pk;
                pk.x = f2us(silu_f(hv[q * 4 + 0] * 0.35355339059327373f));
                pk.y = f2us(silu_f(hv[q * 4 + 1] * 0.35355339059327373f));
                pk.z = f2us(silu_f(hv[q * 4 + 2] * 0.35355339059327373f));
                pk.w = f2us(silu_f(hv[q * 4 + 3] * 0.35355339059327373f));
                *reinterpret_cast<ushort4*>(&hid_s[pA][jb + q * 4]) = pk;
            }
        }
        __syncthreads();
        // ---- stage B: wave wv computes pass wv over [64 edges][64 cols] ----
        {
            f32x4 acc[4][4];
#pragma unroll
            for (int i = 0; i < 4; i++)
#pragma unroll
                for (int t = 0; t < 4; t++) acc[i][t] = 0.0f;
#pragma unroll
            for (int s = 0; s < 2; s++) {
                short8 af[4];
#pragma unroll
                for (int i = 0; i < 4; i++)
                    af[i] = *reinterpret_cast<const short8*>(&hid_s[i * 16 + llo][s * 32 + lhi * 8]);
#pragma unroll
                for (int i = 0; i < 4; i++)
#pragma unroll
                    for (int t = 0; t < 4; t++)
                        acc[i][t] = __builtin_amdgcn_mfma_f32_16x16x32_bf16(af[i], bfr[t][s], acc[i][t], 0, 0, 0);
            }
#pragma unroll
            for (int i = 0; i < 4; i++)
#pragma unroll
                for (int t = 0; t < 4; t++)
#pragma unroll
                    for (int r = 0; r < 4; r++)
                        w_lds[(i * 16 + lhi * 4 + r) * RROW + (t * 16 + llo) * 4 + wv] =
                            f2us(acc[i][t][r] * 0.125f);
        }
        __syncthreads();
        // ---- gather: wave wv accumulates its node's edges within this group ----
        {
            int lo = beg_w > gstart ? beg_w : gstart;
            int gend = gstart + 64; if (gend > end_blk) gend = end_blk;
            int hi = end_w < gend ? end_w : gend;
            for (int idx = lo; idx < hi; idx++) {
                int e = eids[idx];
                int snd = senders[e];
                ushort4 w4 = *reinterpret_cast<const ushort4*>(&w_lds[(idx - gstart) * RROW + lane * 4]);
                ushort4 h4 = *reinterpret_cast<const ushort4*>(h + (long)snd * 256 + lane * 4);
                float w0 = us2f(w4.x), w1 = us2f(w4.y), w2 = us2f(w4.z), w3 = us2f(w4.w);
                float s0 = us2f(h4.x), s1x = us2f(h4.y), s1y = us2f(h4.z), s1z = us2f(h4.w);
                float y0  = us2f(ey0[e]);
                float y1x = us2f(ey1[(long)e * 3 + 0]);
                float y1y = us2f(ey1[(long)e * 3 + 1]);
                float y1z = us2f(ey1[(long)e * 3 + 2]);
                A0a += w0 * s0 * y0;
                A0b += w1 * (s1x * y1x + s1y * y1y + s1z * y1z);
                Ax += w2 * s0 * y1x; Ay += w2 * s0 * y1y; Az += w2 * s0 * y1z;
                Bx += w3 * s1x * y0; By += w3 * s1y * y0; Bz += w3 * s1z * y0;
            }
        }
        __syncthreads();
    }

    const float q = 0.25f;                  // 1/sqrt(avg_neigh)
    const float rs3 = 0.57735026918962576f; // 1/sqrt(3)
    int l = lane;
    a_lds[wv][l] = A0a * q;
    a_lds[wv][64 + l] = A0b * q * rs3;
    a_lds[wv][128 + l] = Ax * q;  a_lds[wv][128 + 64 + l] = Bx * q;
    a_lds[wv][256 + l] = Ay * q;  a_lds[wv][256 + 64 + l] = By * q;
    a_lds[wv][384 + l] = Az * q;  a_lds[wv][384 + 64 + l] = Bz * q;
    __syncthreads();

    int sp = species[node];
    float d0lo = 0.f, d0hi = 0.f, d1x = 0.f, d1y = 0.f, d1z = 0.f;
#pragma unroll 4
    for (int m = 0; m < 128; m++) {
        float am = a_lds[wv][m];
        d0lo += am * us2f(Wd0[(long)m * 128 + l]);
        d0hi += am * us2f(Wd0[(long)m * 128 + 64 + l]);
        float wd1 = us2f(Wd1[(long)m * 64 + l]);
        d1x += a_lds[wv][128 + m] * wd1;
        d1y += a_lds[wv][256 + m] * wd1;
        d1z += a_lds[wv][384 + m] * wd1;
    }
    float sc0lo = 0.f, sc0hi = 0.f, sc1x = 0.f, sc1y = 0.f, sc1z = 0.f;
#pragma unroll 4
    for (int m = 0; m < 64; m++) {
        float xm = us2f(x0[(long)node * 64 + m]);
        sc0lo += xm * us2f(Wsc0[((long)sp * 64 + m) * 128 + l]);
        sc0hi += xm * us2f(Wsc0[((long)sp * 64 + m) * 128 + 64 + l]);
        float w1m = us2f(Wsc1[((long)sp * 64 + m) * 64 + l]);
        sc1x += us2f(x1[(long)node * 192 + m * 3 + 0]) * w1m;
        sc1y += us2f(x1[(long)node * 192 + m * 3 + 1]) * w1m;
        sc1z += us2f(x1[(long)node * 192 + m * 3 + 2]) * w1m;
    }
    const float inv2 = 0.08838834764831845f;  // 1/sqrt(128)
    const float inv  = 0.125f;                // 1/sqrt(64)
    float f0lo = 0.5f * (d0lo * inv2 + sc0lo * inv);
    float f0hi = 0.5f * (d0hi * inv2 + sc0hi * inv);
    float scal = silu_f(f0lo);
    float gate = silu_f(f0hi);
    out[(long)node * 64 + l] = scal;
    long vb = (long)N64 + ((long)node * 64 + l) * 3;
    out[vb + 0] = 0.5f * (d1x * inv2 + sc1x * inv) * gate;
    out[vb + 1] = 0.5f * (d1y * inv2 + sc1y * inv) * gate;
    out[vb + 2] = 0.5f * (d1z * inv2 + sc1z * inv) * gate;
}

// ---------------- host launch --------------------------------------------------
extern "C" void kernel_launch(void* const* d_in, const int* in_sizes, int n_in,
                              void* d_out, int out_size, void* d_ws, size_t ws_size,
                              hipStream_t stream) {
    const int* senders   = (const int*)d_in[5];
    const int* receivers = (const int*)d_in[6];
    const int* species   = (const int*)d_in[7];
    float* out = (float*)d_out;

    char* ws = (char*)d_ws;
    size_t o = 0;
    auto alloc = [&](size_t bytes) { size_t p = o; o = (o + bytes + 255) & ~255UL; return p; };
    int* flag   = (int*)(ws + alloc(4));
    int* cnt    = (int*)(ws + alloc((size_t)NN * 4));
    int* offs   = (int*)(ws + alloc((size_t)(NN + 1) * 4));
    int* cursor = (int*)(ws + alloc((size_t)NN * 4));
    int* eids   = (int*)(ws + alloc((size_t)NE * 4));
    u16* c_x0   = (u16*)(ws + alloc(SB0 * 2));
    u16* c_x1   = (u16*)(ws + alloc((SB1 - SB0) * 2));
    u16* c_ey0  = (u16*)(ws + alloc((SB2 - SB1) * 2));
    u16* c_ey1  = (u16*)(ws + alloc((SB3 - SB2) * 2));
    u16* c_re   = (u16*)(ws + alloc((SB4 - SB3) * 2));
    u16* c_Wup0 = (u16*)(ws + alloc((SB5 - SB4) * 2));
    u16* c_Wup1 = (u16*)(ws + alloc((SB6 - SB5) * 2));
    u16* c_Rw1  = (u16*)(ws + alloc((SB7 - SB6) * 2));
    u16* c_Rw2  = (u16*)(ws + alloc((SB8 - SB7) * 2));
    u16* c_Wd0  = (u16*)(ws + alloc((SB9 - SB8) * 2));
    u16* c_Wd1  = (u16*)(ws + alloc((SB10 - SB9) * 2));
    u16* c_Wsc0 = (u16*)(ws + alloc((SB11 - SB10) * 2));
    u16* c_Wsc1 = (u16*)(ws + alloc((SB12 - SB11) * 2));
    u16* h      = (u16*)(ws + alloc((size_t)NN * 256 * 2));   // [node][64][4]
    // total ~24.5 MB, fixed

    k_sniff<<<1, 64, 0, stream>>>((const u16*)d_in[4], flag);
    k_convert<<<29058, 256, 0, stream>>>(d_in[0], d_in[1], d_in[2], d_in[3], d_in[4],
        d_in[8], d_in[9], d_in[10], d_in[11], d_in[12], d_in[13], d_in[14], d_in[15],
        flag, c_x0, c_x1, c_ey0, c_ey1, c_re,
        c_Wup0, c_Wup1, c_Rw1, c_Rw2, c_Wd0, c_Wd1, c_Wsc0, c_Wsc1);

    (void)hipMemsetAsync(cnt, 0, (size_t)NN * 4, stream);
    k_hist<<<NE / 256, 256, 0, stream>>>(receivers, cnt);
    k_scan<<<1, 256, 0, stream>>>(cnt, offs, cursor);
    k_scatter<<<NE / 256, 256, 0, stream>>>(receivers, cursor, eids);

    k_up_gemm<<<dim3(NN / 256, 4), 256, 0, stream>>>(c_x0, c_x1, c_Wup0, c_Wup1, h);

    k_fused<<<NN / 4, 256, 0, stream>>>(offs, eids, senders, c_re, c_Rw1, c_Rw2, h,
                                        c_ey0, c_ey1, c_x0, c_x1, species,
                                        c_Wd0, c_Wd1, c_Wsc0, c_Wsc1, out);
}

// Round 9
// 665.844 us; speedup vs baseline: 1.0604x; 1.0604x over previous
//
#include <hip/hip_runtime.h>

#define NN 16384          // nodes
#define NE 262144         // edges
#define N64 (NN * 64)

typedef unsigned short u16;
typedef __attribute__((ext_vector_type(8))) short short8;
typedef __attribute__((ext_vector_type(4))) float f32x4;

__device__ __forceinline__ float us2f(u16 u) {
    union { unsigned int i; float f; } v; v.i = ((unsigned int)u) << 16; return v.f;
}
__device__ __forceinline__ u16 f2us(float x) {   // f32 -> bf16 bits, RNE
    union { float f; unsigned int i; } u; u.f = x;
    unsigned int r = u.i + 0x7FFF + ((u.i >> 16) & 1);
    return (u16)(r >> 16);
}
__device__ __forceinline__ float silu_f(float x) { return x / (1.0f + __expf(-x)); }
__device__ __forceinline__ float ldf(const void* p, long i, int f) {
    return f ? ((const float*)p)[i] : us2f(((const u16*)p)[i]);
}

// ---------------- dtype sniff (drives only k_convert) --------------------------
__global__ void k_sniff(const u16* __restrict__ re, int* __restrict__ flag) {
    int t = threadIdx.x;
    int hit = (re[t] >= 0x4000) ? 1 : 0;
    unsigned long long b = __ballot(hit);
    if (t == 0) *flag = (__popcll(b) >= 4) ? 1 : 0;   // 1 => f32 inputs
}

// ---------------- convert every float tensor to a bf16 ws copy ------------------
#define SB0 1048576L
#define SB1 4194304L
#define SB2 4456448L
#define SB3 5242880L
#define SB4 7340032L
#define SB5 7344128L
#define SB6 7348224L
#define SB7 7348736L
#define SB8 7365120L
#define SB9 7381504L
#define SB10 7389696L
#define SB11 7422464L
#define SB12 7438848L   // total; /256 = 29058 blocks

__global__ void k_convert(const void* x0, const void* x1, const void* ey0, const void* ey1,
                          const void* re, const void* Wup0, const void* Wup1, const void* Rw1,
                          const void* Rw2, const void* Wd0, const void* Wd1, const void* Wsc0,
                          const void* Wsc1, const int* __restrict__ flag,
                          u16* c_x0, u16* c_x1, u16* c_ey0, u16* c_ey1, u16* c_re,
                          u16* c_Wup0, u16* c_Wup1, u16* c_Rw1, u16* c_Rw2,
                          u16* c_Wd0, u16* c_Wd1, u16* c_Wsc0, u16* c_Wsc1) {
    long i = (long)blockIdx.x * 256 + threadIdx.x;
    int f = *flag;
    if (i < SB0)       { c_x0[i]          = f2us(ldf(x0, i, f)); }
    else if (i < SB1)  { c_x1[i - SB0]    = f2us(ldf(x1, i - SB0, f)); }
    else if (i < SB2)  { c_ey0[i - SB1]   = f2us(ldf(ey0, i - SB1, f)); }
    else if (i < SB3)  { c_ey1[i - SB2]   = f2us(ldf(ey1, i - SB2, f)); }
    else if (i < SB4)  { c_re[i - SB3]    = f2us(ldf(re, i - SB3, f)); }
    else if (i < SB5)  { c_Wup0[i - SB4]  = f2us(ldf(Wup0, i - SB4, f)); }
    else if (i < SB6)  { c_Wup1[i - SB5]  = f2us(ldf(Wup1, i - SB5, f)); }
    else if (i < SB7)  { c_Rw1[i - SB6]   = f2us(ldf(Rw1, i - SB6, f)); }
    else if (i < SB8)  { c_Rw2[i - SB7]   = f2us(ldf(Rw2, i - SB7, f)); }
    else if (i < SB9)  { c_Wd0[i - SB8]   = f2us(ldf(Wd0, i - SB8, f)); }
    else if (i < SB10) { c_Wd1[i - SB9]   = f2us(ldf(Wd1, i - SB9, f)); }
    else if (i < SB11) { c_Wsc0[i - SB10] = f2us(ldf(Wsc0, i - SB10, f)); }
    else               { c_Wsc1[i - SB11] = f2us(ldf(Wsc1, i - SB11, f)); }
}

// ---------------- CSR build ----------------------------------------------------
__global__ void k_hist(const int* __restrict__ recv, int* __restrict__ cnt) {
    int t = blockIdx.x * 256 + threadIdx.x;
    atomicAdd(&cnt[recv[t]], 1);
}

__global__ void k_scan(const int* __restrict__ cnt, int* __restrict__ offs,
                       int* __restrict__ cursor) {
    __shared__ int sd[256];
    int t = threadIdx.x;
    int base = t * 64;
    const int4* c4 = (const int4*)cnt;
    int loc[64];
#pragma unroll
    for (int i = 0; i < 16; i++) {
        int4 v = c4[t * 16 + i];
        loc[i * 4 + 0] = v.x; loc[i * 4 + 1] = v.y; loc[i * 4 + 2] = v.z; loc[i * 4 + 3] = v.w;
    }
    int sum = 0;
#pragma unroll
    for (int i = 0; i < 64; i++) sum += loc[i];
    sd[t] = sum; __syncthreads();
    for (int off = 1; off < 256; off <<= 1) {
        int v = (t >= off) ? sd[t - off] : 0;
        __syncthreads();
        sd[t] += v;
        __syncthreads();
    }
    int run = sd[t] - sum;
    for (int i = 0; i < 64; i++) {
        offs[base + i] = run; cursor[base + i] = run;
        run += loc[i];
    }
    if (t == 255) offs[NN] = run;
}

// scatter + metadata pack: meta[p] = {snd, y0|y1x<<16, y1y|y1z<<16, e}
__global__ void k_scatter(const int* __restrict__ recv, const int* __restrict__ senders,
                          const u16* __restrict__ ey0, const u16* __restrict__ ey1,
                          int* __restrict__ cursor,
                          int* __restrict__ eids, int4* __restrict__ meta) {
    int e = blockIdx.x * 256 + threadIdx.x;
    int p = atomicAdd(&cursor[recv[e]], 1);
    eids[p] = e;
    unsigned y0  = ey0[e];
    unsigned y1x = ey1[(long)e * 3 + 0];
    unsigned y1y = ey1[(long)e * 3 + 1];
    unsigned y1z = ey1[(long)e * 3 + 2];
    int4 m;
    m.x = senders[e];
    m.y = (int)(y0 | (y1x << 16));
    m.z = (int)(y1y | (y1z << 16));
    m.w = e;
    meta[p] = m;
}

// ---------------- linear_up: h[node][64ch][4comp] interleaved bf16 --------------
__global__ void k_up_gemm(const u16* __restrict__ x0, const u16* __restrict__ x1,
                          const u16* __restrict__ Wup0, const u16* __restrict__ Wup1,
                          u16* __restrict__ h) {
    int inst = blockIdx.y;
    int wv = threadIdx.x >> 6, lane = threadIdx.x & 63;
    int lhi = lane >> 4, llo = lane & 15;
    int mb = blockIdx.x * 256 + wv * 64;
    const u16* B = (inst == 0) ? Wup0 : Wup1;

    short8 bfr[4][2];
#pragma unroll
    for (int t = 0; t < 4; t++)
#pragma unroll
        for (int s = 0; s < 2; s++)
#pragma unroll
            for (int j = 0; j < 8; j++)
                bfr[t][s][j] = (short)B[(long)(s * 32 + lhi * 8 + j) * 64 + t * 16 + llo];

    f32x4 acc[4][4];
#pragma unroll
    for (int i = 0; i < 4; i++)
#pragma unroll
        for (int t = 0; t < 4; t++) acc[i][t] = 0.0f;

#pragma unroll
    for (int s = 0; s < 2; s++) {
        short8 af[4];
#pragma unroll
        for (int i = 0; i < 4; i++) {
            int row = mb + i * 16 + llo;
            if (inst == 0) {
                af[i] = *reinterpret_cast<const short8*>(x0 + (long)row * 64 + s * 32 + lhi * 8);
            } else {
#pragma unroll
                for (int j = 0; j < 8; j++) {
                    int k = s * 32 + lhi * 8 + j;
                    af[i][j] = (short)x1[(long)row * 192 + (long)k * 3 + (inst - 1)];
                }
            }
        }
#pragma unroll
        for (int i = 0; i < 4; i++)
#pragma unroll
            for (int t = 0; t < 4; t++)
                acc[i][t] = __builtin_amdgcn_mfma_f32_16x16x32_bf16(af[i], bfr[t][s], acc[i][t], 0, 0, 0);
    }
#pragma unroll
    for (int i = 0; i < 4; i++)
#pragma unroll
        for (int t = 0; t < 4; t++)
#pragma unroll
            for (int r = 0; r < 4; r++)
                h[(long)(mb + i * 16 + lhi * 4 + r) * 256 + (t * 16 + llo) * 4 + inst] =
                    f2us(acc[i][t][r] * 0.125f);
}

// ---------------- radial MLP: barrier-free, CSR order, wk[idx][pass][ch] --------
// Block = 4 waves; wave wv computes pass wv. Each wave processes 16 tiles of 16
// edges. Stage A (hid) in registers (redundant across waves, cheap); MFMA; 2 KB
// private LDS transpose; full-line coalesced flush. No __syncthreads anywhere.
#define RTR 72   // tr row stride (u16): 144 B, 16B-aligned
__global__ void k_radialB(const u16* __restrict__ re, const u16* __restrict__ Rw1,
                          const u16* __restrict__ Rw2,
                          const int* __restrict__ eids, const int* __restrict__ offs,
                          u16* __restrict__ wkc, int n0, int n1) {
    __shared__ u16 tr[4][16 * RTR];   // 9.2 KB total
    int tid = threadIdx.x;
    int wv = tid >> 6, lane = tid & 63, lhi = lane >> 4, llo = lane & 15;
    int cbase = offs[n0], cend = offs[n1];
    int s0 = cbase + blockIdx.x * 256;
    if (s0 >= cend) return;

    // Rw1 columns this lane needs: cols s*32 + lhi*8 + j, all 8 rows (packed bf16)
    short8 w1reg[2][8];
#pragma unroll
    for (int s = 0; s < 2; s++)
#pragma unroll
        for (int r = 0; r < 8; r++)
            w1reg[s][r] = *reinterpret_cast<const short8*>(Rw1 + r * 64 + s * 32 + lhi * 8);

    // B fragments of Rw2 for pass wv
    short8 bfr[4][2];
#pragma unroll
    for (int n = 0; n < 4; n++)
#pragma unroll
        for (int s = 0; s < 2; s++)
#pragma unroll
            for (int j = 0; j < 8; j++)
                bfr[n][s][j] = (short)Rw2[(long)(s * 32 + lhi * 8 + j) * 256 + wv * 64 + n * 16 + llo];

    int row = lane >> 2, q = lane & 3;   // flush roles

    for (int t16 = 0; t16 < 16; t16++) {
        int tb = s0 + t16 * 16;
        if (tb >= cend) break;           // uniform
        int pos = tb + llo;
        if (pos >= cend) pos = cbase;    // filler
        int e = eids[pos];
        // stage A: hid[e][k] for k = s*32 + lhi*8 + j  (A-fragment layout, m=llo)
        short8 r8 = *reinterpret_cast<const short8*>(re + (long)e * 8);
        float rr[8];
#pragma unroll
        for (int r = 0; r < 8; r++) rr[r] = us2f((u16)r8[r]);
        short8 af[2];
#pragma unroll
        for (int s = 0; s < 2; s++)
#pragma unroll
            for (int j = 0; j < 8; j++) {
                float acc = rr[0] * us2f((u16)w1reg[s][0][j]);
#pragma unroll
                for (int r = 1; r < 8; r++) acc += rr[r] * us2f((u16)w1reg[s][r][j]);
                af[s][j] = (short)f2us(silu_f(acc * 0.35355339059327373f));
            }
        // MFMA: 4 N-tiles (64 cols of this pass), K=64 in 2 steps
        f32x4 acc[4];
#pragma unroll
        for (int n = 0; n < 4; n++) acc[n] = 0.0f;
#pragma unroll
        for (int n = 0; n < 4; n++) {
            acc[n] = __builtin_amdgcn_mfma_f32_16x16x32_bf16(af[0], bfr[n][0], acc[n], 0, 0, 0);
            acc[n] = __builtin_amdgcn_mfma_f32_16x16x32_bf16(af[1], bfr[n][1], acc[n], 0, 0, 0);
        }
        // private transpose: tr[edge-in-tile][col]
#pragma unroll
        for (int n = 0; n < 4; n++)
#pragma unroll
            for (int r = 0; r < 4; r++)
                tr[wv][(lhi * 4 + r) * RTR + n * 16 + llo] = f2us(acc[n][r] * 0.125f);
        // flush: lane covers 32 B of edge `row`'s 128-B pass-segment
        f32x4 v0 = *reinterpret_cast<const f32x4*>(&tr[wv][row * RTR + q * 16]);
        f32x4 v1 = *reinterpret_cast<const f32x4*>(&tr[wv][row * RTR + q * 16 + 8]);
        long ob = (long)(tb - cbase + row) * 256 + wv * 64 + q * 16;
        *reinterpret_cast<f32x4*>(wkc + ob) = v0;
        *reinterpret_cast<f32x4*>(wkc + ob + 8) = v1;
    }
}

// ---------------- gather + linear_down + self-connection + gate -----------------
__global__ void k_node(const int* __restrict__ offs, const u16* __restrict__ wkc,
                       const int4* __restrict__ meta, const u16* __restrict__ h,
                       const u16* __restrict__ x0, const u16* __restrict__ x1,
                       const int* __restrict__ species,
                       const u16* __restrict__ Wd0, const u16* __restrict__ Wd1,
                       const u16* __restrict__ Wsc0, const u16* __restrict__ Wsc1,
                       float* __restrict__ out, int n0, int cap) {
    __shared__ float a_lds[4][512];
    int wv = threadIdx.x >> 6, l = threadIdx.x & 63;
    int node = n0 + blockIdx.x * 4 + wv;
    int cbase = offs[n0];
    int beg = offs[node] - cbase, end = offs[node + 1] - cbase;
    if (beg > cap) beg = cap;
    if (end > cap) end = cap;

    float A0a = 0.f, A0b = 0.f;
    float Ax = 0.f, Ay = 0.f, Az = 0.f;
    float Bx = 0.f, By = 0.f, Bz = 0.f;

    int idx = beg;
    for (; idx + 2 <= end; idx += 2) {
        int4 m0 = meta[cbase + idx];
        int4 m1 = meta[cbase + idx + 1];
        const u16* wr0 = wkc + (long)idx * 256;
        const u16* wr1 = wkc + (long)(idx + 1) * 256;
        float w00 = us2f(wr0[l]),      w01 = us2f(wr0[64 + l]);
        float w02 = us2f(wr0[128 + l]), w03 = us2f(wr0[192 + l]);
        float w10 = us2f(wr1[l]),      w11 = us2f(wr1[64 + l]);
        float w12 = us2f(wr1[128 + l]), w13 = us2f(wr1[192 + l]);
        ushort4 h0v = *reinterpret_cast<const ushort4*>(h + (long)m0.x * 256 + l * 4);
        ushort4 h1v = *reinterpret_cast<const ushort4*>(h + (long)m1.x * 256 + l * 4);
        {
            float y0  = us2f((u16)((unsigned)m0.y & 0xffff));
            float y1x = us2f((u16)((unsigned)m0.y >> 16));
            float y1y = us2f((u16)((unsigned)m0.z & 0xffff));
            float y1z = us2f((u16)((unsigned)m0.z >> 16));
            float s0 = us2f(h0v.x), s1x = us2f(h0v.y), s1y = us2f(h0v.z), s1z = us2f(h0v.w);
            A0a += w00 * s0 * y0;
            A0b += w01 * (s1x * y1x + s1y * y1y + s1z * y1z);
            Ax += w02 * s0 * y1x; Ay += w02 * s0 * y1y; Az += w02 * s0 * y1z;
            Bx += w03 * s1x * y0; By += w03 * s1y * y0; Bz += w03 * s1z * y0;
        }
        {
            float y0  = us2f((u16)((unsigned)m1.y & 0xffff));
            float y1x = us2f((u16)((unsigned)m1.y >> 16));
            float y1y = us2f((u16)((unsigned)m1.z & 0xffff));
            float y1z = us2f((u16)((unsigned)m1.z >> 16));
            float s0 = us2f(h1v.x), s1x = us2f(h1v.y), s1y = us2f(h1v.z), s1z = us2f(h1v.w);
            A0a += w10 * s0 * y0;
            A0b += w11 * (s1x * y1x + s1y * y1y + s1z * y1z);
            Ax += w12 * s0 * y1x; Ay += w12 * s0 * y1y; Az += w12 * s0 * y1z;
            Bx += w13 * s1x * y0; By += w13 * s1y * y0; Bz += w13 * s1z * y0;
        }
    }
    if (idx < end) {
        int4 m0 = meta[cbase + idx];
        const u16* wr0 = wkc + (long)idx * 256;
        float w00 = us2f(wr0[l]),       w01 = us2f(wr0[64 + l]);
        float w02 = us2f(wr0[128 + l]), w03 = us2f(wr0[192 + l]);
        ushort4 h0v = *reinterpret_cast<const ushort4*>(h + (long)m0.x * 256 + l * 4);
        float y0  = us2f((u16)((unsigned)m0.y & 0xffff));
        float y1x = us2f((u16)((unsigned)m0.y >> 16));
        float y1y = us2f((u16)((unsigned)m0.z & 0xffff));
        float y1z = us2f((u16)((unsigned)m0.z >> 16));
        float s0 = us2f(h0v.x), s1x = us2f(h0v.y), s1y = us2f(h0v.z), s1z = us2f(h0v.w);
        A0a += w00 * s0 * y0;
        A0b += w01 * (s1x * y1x + s1y * y1y + s1z * y1z);
        Ax += w02 * s0 * y1x; Ay += w02 * s0 * y1y; Az += w02 * s0 * y1z;
        Bx += w03 * s1x * y0; By += w03 * s1y * y0; Bz += w03 * s1z * y0;
    }

    const float qn = 0.25f;                 // 1/sqrt(avg_neigh)
    const float rs3 = 0.57735026918962576f; // 1/sqrt(3)
    a_lds[wv][l] = A0a * qn;
    a_lds[wv][64 + l] = A0b * qn * rs3;
    a_lds[wv][128 + l] = Ax * qn;  a_lds[wv][128 + 64 + l] = Bx * qn;
    a_lds[wv][256 + l] = Ay * qn;  a_lds[wv][256 + 64 + l] = By * qn;
    a_lds[wv][384 + l] = Az * qn;  a_lds[wv][384 + 64 + l] = Bz * qn;
    __syncthreads();

    int sp = species[node];
    float d0lo = 0.f, d0hi = 0.f, d1x = 0.f, d1y = 0.f, d1z = 0.f;
#pragma unroll 4
    for (int m = 0; m < 128; m++) {
        float am = a_lds[wv][m];
        d0lo += am * us2f(Wd0[(long)m * 128 + l]);
        d0hi += am * us2f(Wd0[(long)m * 128 + 64 + l]);
        float wd1 = us2f(Wd1[(long)m * 64 + l]);
        d1x += a_lds[wv][128 + m] * wd1;
        d1y += a_lds[wv][256 + m] * wd1;
        d1z += a_lds[wv][384 + m] * wd1;
    }
    float sc0lo = 0.f, sc0hi = 0.f, sc1x = 0.f, sc1y = 0.f, sc1z = 0.f;
#pragma unroll 4
    for (int m = 0; m < 64; m++) {
        float xm = us2f(x0[(long)node * 64 + m]);
        sc0lo += xm * us2f(Wsc0[((long)sp * 64 + m) * 128 + l]);
        sc0hi += xm * us2f(Wsc0[((long)sp * 64 + m) * 128 + 64 + l]);
        float w1m = us2f(Wsc1[((long)sp * 64 + m) * 64 + l]);
        sc1x += us2f(x1[(long)node * 192 + m * 3 + 0]) * w1m;
        sc1y += us2f(x1[(long)node * 192 + m * 3 + 1]) * w1m;
        sc1z += us2f(x1[(long)node * 192 + m * 3 + 2]) * w1m;
    }
    const float inv2 = 0.08838834764831845f;  // 1/sqrt(128)
    const float inv  = 0.125f;                // 1/sqrt(64)
    float f0lo = 0.5f * (d0lo * inv2 + sc0lo * inv);
    float f0hi = 0.5f * (d0hi * inv2 + sc0hi * inv);
    float scal = silu_f(f0lo);
    float gate = silu_f(f0hi);
    out[(long)node * 64 + l] = scal;
    long vb = (long)N64 + ((long)node * 64 + l) * 3;
    out[vb + 0] = 0.5f * (d1x * inv2 + sc1x * inv) * gate;
    out[vb + 1] = 0.5f * (d1y * inv2 + sc1y * inv) * gate;
    out[vb + 2] = 0.5f * (d1z * inv2 + sc1z * inv) * gate;
}

// ---------------- host launch --------------------------------------------------
extern "C" void kernel_launch(void* const* d_in, const int* in_sizes, int n_in,
                              void* d_out, int out_size, void* d_ws, size_t ws_size,
                              hipStream_t stream) {
    const int* senders   = (const int*)d_in[5];
    const int* receivers = (const int*)d_in[6];
    const int* species   = (const int*)d_in[7];
    float* out = (float*)d_out;

    char* ws = (char*)d_ws;
    size_t o = 0;
    auto alloc = [&](size_t bytes) { size_t p = o; o = (o + bytes + 255) & ~255UL; return p; };
    int* flag   = (int*)(ws + alloc(4));
    int* cnt    = (int*)(ws + alloc((size_t)NN * 4));
    int* offs   = (int*)(ws + alloc((size_t)(NN + 1) * 4));
    int* cursor = (int*)(ws + alloc((size_t)NN * 4));
    int* eids   = (int*)(ws + alloc((size_t)NE * 4));
    int4* meta  = (int4*)(ws + alloc((size_t)NE * 16));
    u16* c_x0   = (u16*)(ws + alloc(SB0 * 2));
    u16* c_x1   = (u16*)(ws + alloc((SB1 - SB0) * 2));
    u16* c_ey0  = (u16*)(ws + alloc((SB2 - SB1) * 2));
    u16* c_ey1  = (u16*)(ws + alloc((SB3 - SB2) * 2));
    u16* c_re   = (u16*)(ws + alloc((SB4 - SB3) * 2));
    u16* c_Wup0 = (u16*)(ws + alloc((SB5 - SB4) * 2));
    u16* c_Wup1 = (u16*)(ws + alloc((SB6 - SB5) * 2));
    u16* c_Rw1  = (u16*)(ws + alloc((SB7 - SB6) * 2));
    u16* c_Rw2  = (u16*)(ws + alloc((SB8 - SB7) * 2));
    u16* c_Wd0  = (u16*)(ws + alloc((SB9 - SB8) * 2));
    u16* c_Wd1  = (u16*)(ws + alloc((SB10 - SB9) * 2));
    u16* c_Wsc0 = (u16*)(ws + alloc((SB11 - SB10) * 2));
    u16* c_Wsc1 = (u16*)(ws + alloc((SB12 - SB11) * 2));
    u16* h      = (u16*)(ws + alloc((size_t)NN * 256 * 2));   // [node][64][4]
    size_t fixed = o;                       // ~28.5 MB
    // wk chunk: [CAP][4 pass][64 ch] bf16; pick fewest chunks that fit ws_size
    int C = 128;
    for (int c = 2; c <= 128; c <<= 1) {
        size_t cap = (size_t)NE / c + 2048;
        if (fixed + cap * 512 <= ws_size) { C = c; break; }
    }
    int CAP = NE / C + 2048;                // multiple of 256
    u16* wk = (u16*)(ws + alloc((size_t)CAP * 512));
    int NNC = NN / C;

    k_sniff<<<1, 64, 0, stream>>>((const u16*)d_in[4], flag);
    k_convert<<<29058, 256, 0, stream>>>(d_in[0], d_in[1], d_in[2], d_in[3], d_in[4],
        d_in[8], d_in[9], d_in[10], d_in[11], d_in[12], d_in[13], d_in[14], d_in[15],
        flag, c_x0, c_x1, c_ey0, c_ey1, c_re,
        c_Wup0, c_Wup1, c_Rw1, c_Rw2, c_Wd0, c_Wd1, c_Wsc0, c_Wsc1);

    (void)hipMemsetAsync(cnt, 0, (size_t)NN * 4, stream);
    k_hist<<<NE / 256, 256, 0, stream>>>(receivers, cnt);
    k_scan<<<1, 256, 0, stream>>>(cnt, offs, cursor);
    k_scatter<<<NE / 256, 256, 0, stream>>>(receivers, senders, c_ey0, c_ey1,
                                            cursor, eids, meta);

    k_up_gemm<<<dim3(NN / 256, 4), 256, 0, stream>>>(c_x0, c_x1, c_Wup0, c_Wup1, h);

    for (int c = 0; c < C; c++) {
        int n0 = c * NNC, n1 = n0 + NNC;
        k_radialB<<<CAP / 256, 256, 0, stream>>>(c_re, c_Rw1, c_Rw2, eids, offs, wk, n0, n1);
        k_node<<<NNC / 4, 256, 0, stream>>>(offs, wk, meta, h, c_x0, c_x1, species,
                                            c_Wd0, c_Wd1, c_Wsc0, c_Wsc1, out, n0, CAP);
    }
}

// Round 10
// 390.586 us; speedup vs baseline: 1.8077x; 1.7047x over previous
//
#include <hip/hip_runtime.h>

#define NN 16384          // nodes
#define NE 262144         // edges
#define N64 (NN * 64)

typedef unsigned short u16;
typedef __attribute__((ext_vector_type(8))) short short8;
typedef __attribute__((ext_vector_type(4))) float f32x4;

__device__ __forceinline__ float us2f(u16 u) {
    union { unsigned int i; float f; } v; v.i = ((unsigned int)u) << 16; return v.f;
}
__device__ __forceinline__ u16 f2us(float x) {   // f32 -> bf16 bits, RNE
    union { float f; unsigned int i; } u; u.f = x;
    unsigned int r = u.i + 0x7FFF + ((u.i >> 16) & 1);
    return (u16)(r >> 16);
}
__device__ __forceinline__ float silu_f(float x) { return x / (1.0f + __expf(-x)); }
__device__ __forceinline__ float ldf(const void* p, long i, int f) {
    return f ? ((const float*)p)[i] : us2f(((const u16*)p)[i]);
}

// ---------------- dtype sniff (drives only k_convert) --------------------------
__global__ void k_sniff(const u16* __restrict__ re, int* __restrict__ flag) {
    int t = threadIdx.x;
    int hit = (re[t] >= 0x4000) ? 1 : 0;
    unsigned long long b = __ballot(hit);
    if (t == 0) *flag = (__popcll(b) >= 4) ? 1 : 0;   // 1 => f32 inputs
}

// ---------------- convert every float tensor to a bf16 ws copy ------------------
#define SB0 1048576L
#define SB1 4194304L
#define SB2 4456448L
#define SB3 5242880L
#define SB4 7340032L
#define SB5 7344128L
#define SB6 7348224L
#define SB7 7348736L
#define SB8 7365120L
#define SB9 7381504L
#define SB10 7389696L
#define SB11 7422464L
#define SB12 7438848L   // total; /256 = 29058 blocks

__global__ void k_convert(const void* x0, const void* x1, const void* ey0, const void* ey1,
                          const void* re, const void* Wup0, const void* Wup1, const void* Rw1,
                          const void* Rw2, const void* Wd0, const void* Wd1, const void* Wsc0,
                          const void* Wsc1, const int* __restrict__ flag,
                          u16* c_x0, u16* c_x1, u16* c_ey0, u16* c_ey1, u16* c_re,
                          u16* c_Wup0, u16* c_Wup1, u16* c_Rw1, u16* c_Rw2,
                          u16* c_Wd0, u16* c_Wd1, u16* c_Wsc0, u16* c_Wsc1) {
    long i = (long)blockIdx.x * 256 + threadIdx.x;
    int f = *flag;
    if (i < SB0)       { c_x0[i]          = f2us(ldf(x0, i, f)); }
    else if (i < SB1)  { c_x1[i - SB0]    = f2us(ldf(x1, i - SB0, f)); }
    else if (i < SB2)  { c_ey0[i - SB1]   = f2us(ldf(ey0, i - SB1, f)); }
    else if (i < SB3)  { c_ey1[i - SB2]   = f2us(ldf(ey1, i - SB2, f)); }
    else if (i < SB4)  { c_re[i - SB3]    = f2us(ldf(re, i - SB3, f)); }
    else if (i < SB5)  { c_Wup0[i - SB4]  = f2us(ldf(Wup0, i - SB4, f)); }
    else if (i < SB6)  { c_Wup1[i - SB5]  = f2us(ldf(Wup1, i - SB5, f)); }
    else if (i < SB7)  { c_Rw1[i - SB6]   = f2us(ldf(Rw1, i - SB6, f)); }
    else if (i < SB8)  { c_Rw2[i - SB7]   = f2us(ldf(Rw2, i - SB7, f)); }
    else if (i < SB9)  { c_Wd0[i - SB8]   = f2us(ldf(Wd0, i - SB8, f)); }
    else if (i < SB10) { c_Wd1[i - SB9]   = f2us(ldf(Wd1, i - SB9, f)); }
    else if (i < SB11) { c_Wsc0[i - SB10] = f2us(ldf(Wsc0, i - SB10, f)); }
    else               { c_Wsc1[i - SB11] = f2us(ldf(Wsc1, i - SB11, f)); }
}

// ---------------- CSR build ----------------------------------------------------
__global__ void k_hist(const int* __restrict__ recv, int* __restrict__ cnt) {
    int t = blockIdx.x * 256 + threadIdx.x;
    atomicAdd(&cnt[recv[t]], 1);
}

__global__ void k_scan(const int* __restrict__ cnt, int* __restrict__ offs,
                       int* __restrict__ cursor) {
    __shared__ int sd[256];
    int t = threadIdx.x;
    int base = t * 64;
    const int4* c4 = (const int4*)cnt;
    int loc[64];
#pragma unroll
    for (int i = 0; i < 16; i++) {
        int4 v = c4[t * 16 + i];
        loc[i * 4 + 0] = v.x; loc[i * 4 + 1] = v.y; loc[i * 4 + 2] = v.z; loc[i * 4 + 3] = v.w;
    }
    int sum = 0;
#pragma unroll
    for (int i = 0; i < 64; i++) sum += loc[i];
    sd[t] = sum; __syncthreads();
    for (int off = 1; off < 256; off <<= 1) {
        int v = (t >= off) ? sd[t - off] : 0;
        __syncthreads();
        sd[t] += v;
        __syncthreads();
    }
    int run = sd[t] - sum;
    for (int i = 0; i < 64; i++) {
        offs[base + i] = run; cursor[base + i] = run;
        run += loc[i];
    }
    if (t == 255) offs[NN] = run;
}

// scatter: cpos[e] = CSR position; meta[p] = {snd, y0|y1x<<16, y1y|y1z<<16, e}
__global__ void k_scatter(const int* __restrict__ recv, const int* __restrict__ senders,
                          const u16* __restrict__ ey0, const u16* __restrict__ ey1,
                          int* __restrict__ cursor,
                          int* __restrict__ cpos, int4* __restrict__ meta) {
    int e = blockIdx.x * 256 + threadIdx.x;
    int p = atomicAdd(&cursor[recv[e]], 1);
    cpos[e] = p;
    unsigned y0  = ey0[e];
    unsigned y1x = ey1[(long)e * 3 + 0];
    unsigned y1y = ey1[(long)e * 3 + 1];
    unsigned y1z = ey1[(long)e * 3 + 2];
    int4 m;
    m.x = senders[e];
    m.y = (int)(y0 | (y1x << 16));
    m.z = (int)(y1y | (y1z << 16));
    m.w = e;
    meta[p] = m;
}

// ---------------- linear_up: h[node][64ch][4comp] interleaved bf16 --------------
__global__ void k_up_gemm(const u16* __restrict__ x0, const u16* __restrict__ x1,
                          const u16* __restrict__ Wup0, const u16* __restrict__ Wup1,
                          u16* __restrict__ h) {
    int inst = blockIdx.y;
    int wv = threadIdx.x >> 6, lane = threadIdx.x & 63;
    int lhi = lane >> 4, llo = lane & 15;
    int mb = blockIdx.x * 256 + wv * 64;
    const u16* B = (inst == 0) ? Wup0 : Wup1;

    short8 bfr[4][2];
#pragma unroll
    for (int t = 0; t < 4; t++)
#pragma unroll
        for (int s = 0; s < 2; s++)
#pragma unroll
            for (int j = 0; j < 8; j++)
                bfr[t][s][j] = (short)B[(long)(s * 32 + lhi * 8 + j) * 64 + t * 16 + llo];

    f32x4 acc[4][4];
#pragma unroll
    for (int i = 0; i < 4; i++)
#pragma unroll
        for (int t = 0; t < 4; t++) acc[i][t] = 0.0f;

#pragma unroll
    for (int s = 0; s < 2; s++) {
        short8 af[4];
#pragma unroll
        for (int i = 0; i < 4; i++) {
            int row = mb + i * 16 + llo;
            if (inst == 0) {
                af[i] = *reinterpret_cast<const short8*>(x0 + (long)row * 64 + s * 32 + lhi * 8);
            } else {
#pragma unroll
                for (int j = 0; j < 8; j++) {
                    int k = s * 32 + lhi * 8 + j;
                    af[i][j] = (short)x1[(long)row * 192 + (long)k * 3 + (inst - 1)];
                }
            }
        }
#pragma unroll
        for (int i = 0; i < 4; i++)
#pragma unroll
            for (int t = 0; t < 4; t++)
                acc[i][t] = __builtin_amdgcn_mfma_f32_16x16x32_bf16(af[i], bfr[t][s], acc[i][t], 0, 0, 0);
    }
#pragma unroll
    for (int i = 0; i < 4; i++)
#pragma unroll
        for (int t = 0; t < 4; t++)
#pragma unroll
            for (int r = 0; r < 4; r++)
                h[(long)(mb + i * 16 + lhi * 4 + r) * 256 + (t * 16 + llo) * 4 + inst] =
                    f2us(acc[i][t][r] * 0.125f);
}

// ---------------- radial MLP: DENSE edge order, scatter to CSR records ----------
// Block = 64 edges (e0 = blockIdx.x*64). Stage A block-coop -> hid_s; wave wv
// computes pass wv via MFMA; block transpose -> w_lds[edge][pass*64+ch]; flush
// full 512-B records to wk[cpos[e]-p0] when cpos in [p0,p1). Coalesced re reads,
// full-line record writes.
#define RROW 272   // w_lds row stride (u16): 544 B
__global__ void k_radialE(const u16* __restrict__ re, const u16* __restrict__ Rw1,
                          const u16* __restrict__ Rw2, const int* __restrict__ cpos,
                          const int* __restrict__ offs,
                          u16* __restrict__ wkc, int n0, int n1, int cap) {
    __shared__ u16 hid_s[64][72];        // 9.2 KB
    __shared__ u16 w_lds[64 * RROW];     // 34.8 KB
    int tid = threadIdx.x;
    int wv = tid >> 6, lane = tid & 63, lhi = lane >> 4, llo = lane & 15;
    int e0 = blockIdx.x * 64;
    int p0 = offs[n0];
    int p1 = offs[n1];
    if (p1 > p0 + cap) p1 = p0 + cap;

    // ---- stage A: hid = silu(re[e] @ Rw1 / sqrt(8)), thread t -> edge t>>2, cols (t&3)*16..+16
    {
        int el = tid >> 2;
        int jb = (tid & 3) * 16;
        int e = e0 + el;
        short8 r8 = *reinterpret_cast<const short8*>(re + (long)e * 8);
        float rr[8];
#pragma unroll
        for (int r = 0; r < 8; r++) rr[r] = us2f((u16)r8[r]);
        float hv[16];
#pragma unroll
        for (int q = 0; q < 2; q++) {
            short8 w8 = *reinterpret_cast<const short8*>(Rw1 + jb + q * 8);
#pragma unroll
            for (int j = 0; j < 8; j++) hv[q * 8 + j] = rr[0] * us2f((u16)w8[j]);
        }
#pragma unroll
        for (int r = 1; r < 8; r++) {
#pragma unroll
            for (int q = 0; q < 2; q++) {
                short8 w8 = *reinterpret_cast<const short8*>(Rw1 + (long)r * 64 + jb + q * 8);
#pragma unroll
                for (int j = 0; j < 8; j++) hv[q * 8 + j] += rr[r] * us2f((u16)w8[j]);
            }
        }
#pragma unroll
        for (int q = 0; q < 4; q++) {
            ushort4 pk;
            pk.x = f2us(silu_f(hv[q * 4 + 0] * 0.35355339059327373f));
            pk.y = f2us(silu_f(hv[q * 4 + 1] * 0.35355339059327373f));
            pk.z = f2us(silu_f(hv[q * 4 + 2] * 0.35355339059327373f));
            pk.w = f2us(silu_f(hv[q * 4 + 3] * 0.35355339059327373f));
            *reinterpret_cast<ushort4*>(&hid_s[el][jb + q * 4]) = pk;
        }
    }
    __syncthreads();
    // ---- stage B: wave wv computes pass wv over [64 edges][64 cols] ----
    {
        short8 bfr[4][2];
#pragma unroll
        for (int t = 0; t < 4; t++)
#pragma unroll
            for (int s = 0; s < 2; s++)
#pragma unroll
                for (int j = 0; j < 8; j++)
                    bfr[t][s][j] = (short)Rw2[(long)(s * 32 + lhi * 8 + j) * 256 + wv * 64 + t * 16 + llo];
        f32x4 acc[4][4];
#pragma unroll
        for (int i = 0; i < 4; i++)
#pragma unroll
            for (int t = 0; t < 4; t++) acc[i][t] = 0.0f;
#pragma unroll
        for (int s = 0; s < 2; s++) {
            short8 af[4];
#pragma unroll
            for (int i = 0; i < 4; i++)
                af[i] = *reinterpret_cast<const short8*>(&hid_s[i * 16 + llo][s * 32 + lhi * 8]);
#pragma unroll
            for (int i = 0; i < 4; i++)
#pragma unroll
                for (int t = 0; t < 4; t++)
                    acc[i][t] = __builtin_amdgcn_mfma_f32_16x16x32_bf16(af[i], bfr[t][s], acc[i][t], 0, 0, 0);
        }
        // transpose into w_lds[edge][pass*64 + ch]
#pragma unroll
        for (int i = 0; i < 4; i++)
#pragma unroll
            for (int t = 0; t < 4; t++)
#pragma unroll
                for (int r = 0; r < 4; r++)
                    w_lds[(i * 16 + lhi * 4 + r) * RROW + wv * 64 + t * 16 + llo] =
                        f2us(acc[i][t][r] * 0.125f);
    }
    __syncthreads();
    // ---- flush: thread t -> edge i = t>>2, quarter q = t&3 (128 B contiguous) ----
    {
        int i = tid >> 2, q = tid & 3;
        int cp = cpos[e0 + i];
        if (cp >= p0 && cp < p1) {
            const u16* src = &w_lds[i * RROW + q * 64];
            u16* dst = wkc + (long)(cp - p0) * 256 + q * 64;
#pragma unroll
            for (int j = 0; j < 8; j++)
                *reinterpret_cast<f32x4*>(dst + j * 8) = *reinterpret_cast<const f32x4*>(src + j * 8);
        }
    }
}

// ---------------- gather + linear_down + self-connection + gate -----------------
__global__ void k_node(const int* __restrict__ offs, const u16* __restrict__ wkc,
                       const int4* __restrict__ meta, const u16* __restrict__ h,
                       const u16* __restrict__ x0, const u16* __restrict__ x1,
                       const int* __restrict__ species,
                       const u16* __restrict__ Wd0, const u16* __restrict__ Wd1,
                       const u16* __restrict__ Wsc0, const u16* __restrict__ Wsc1,
                       float* __restrict__ out, int n0, int cap) {
    __shared__ float a_lds[4][512];
    int wv = threadIdx.x >> 6, l = threadIdx.x & 63;
    int node = n0 + blockIdx.x * 4 + wv;
    int cbase = offs[n0];
    int beg = offs[node] - cbase, end = offs[node + 1] - cbase;
    if (beg > cap) beg = cap;
    if (end > cap) end = cap;

    float A0a = 0.f, A0b = 0.f;
    float Ax = 0.f, Ay = 0.f, Az = 0.f;
    float Bx = 0.f, By = 0.f, Bz = 0.f;

    int idx = beg;
    for (; idx + 2 <= end; idx += 2) {
        int4 m0 = meta[cbase + idx];
        int4 m1 = meta[cbase + idx + 1];
        const u16* wr0 = wkc + (long)idx * 256;
        const u16* wr1 = wkc + (long)(idx + 1) * 256;
        float w00 = us2f(wr0[l]),      w01 = us2f(wr0[64 + l]);
        float w02 = us2f(wr0[128 + l]), w03 = us2f(wr0[192 + l]);
        float w10 = us2f(wr1[l]),      w11 = us2f(wr1[64 + l]);
        float w12 = us2f(wr1[128 + l]), w13 = us2f(wr1[192 + l]);
        ushort4 h0v = *reinterpret_cast<const ushort4*>(h + (long)m0.x * 256 + l * 4);
        ushort4 h1v = *reinterpret_cast<const ushort4*>(h + (long)m1.x * 256 + l * 4);
        {
            float y0  = us2f((u16)((unsigned)m0.y & 0xffff));
            float y1x = us2f((u16)((unsigned)m0.y >> 16));
            float y1y = us2f((u16)((unsigned)m0.z & 0xffff));
            float y1z = us2f((u16)((unsigned)m0.z >> 16));
            float s0 = us2f(h0v.x), s1x = us2f(h0v.y), s1y = us2f(h0v.z), s1z = us2f(h0v.w);
            A0a += w00 * s0 * y0;
            A0b += w01 * (s1x * y1x + s1y * y1y + s1z * y1z);
            Ax += w02 * s0 * y1x; Ay += w02 * s0 * y1y; Az += w02 * s0 * y1z;
            Bx += w03 * s1x * y0; By += w03 * s1y * y0; Bz += w03 * s1z * y0;
        }
        {
            float y0  = us2f((u16)((unsigned)m1.y & 0xffff));
            float y1x = us2f((u16)((unsigned)m1.y >> 16));
            float y1y = us2f((u16)((unsigned)m1.z & 0xffff));
            float y1z = us2f((u16)((unsigned)m1.z >> 16));
            float s0 = us2f(h1v.x), s1x = us2f(h1v.y), s1y = us2f(h1v.z), s1z = us2f(h1v.w);
            A0a += w10 * s0 * y0;
            A0b += w11 * (s1x * y1x + s1y * y1y + s1z * y1z);
            Ax += w12 * s0 * y1x; Ay += w12 * s0 * y1y; Az += w12 * s0 * y1z;
            Bx += w13 * s1x * y0; By += w13 * s1y * y0; Bz += w13 * s1z * y0;
        }
    }
    if (idx < end) {
        int4 m0 = meta[cbase + idx];
        const u16* wr0 = wkc + (long)idx * 256;
        float w00 = us2f(wr0[l]),       w01 = us2f(wr0[64 + l]);
        float w02 = us2f(wr0[128 + l]), w03 = us2f(wr0[192 + l]);
        ushort4 h0v = *reinterpret_cast<const ushort4*>(h + (long)m0.x * 256 + l * 4);
        float y0  = us2f((u16)((unsigned)m0.y & 0xffff));
        float y1x = us2f((u16)((unsigned)m0.y >> 16));
        float y1y = us2f((u16)((unsigned)m0.z & 0xffff));
        float y1z = us2f((u16)((unsigned)m0.z >> 16));
        float s0 = us2f(h0v.x), s1x = us2f(h0v.y), s1y = us2f(h0v.z), s1z = us2f(h0v.w);
        A0a += w00 * s0 * y0;
        A0b += w01 * (s1x * y1x + s1y * y1y + s1z * y1z);
        Ax += w02 * s0 * y1x; Ay += w02 * s0 * y1y; Az += w02 * s0 * y1z;
        Bx += w03 * s1x * y0; By += w03 * s1y * y0; Bz += w03 * s1z * y0;
    }

    const float qn = 0.25f;                 // 1/sqrt(avg_neigh)
    const float rs3 = 0.57735026918962576f; // 1/sqrt(3)
    a_lds[wv][l] = A0a * qn;
    a_lds[wv][64 + l] = A0b * qn * rs3;
    a_lds[wv][128 + l] = Ax * qn;  a_lds[wv][128 + 64 + l] = Bx * qn;
    a_lds[wv][256 + l] = Ay * qn;  a_lds[wv][256 + 64 + l] = By * qn;
    a_lds[wv][384 + l] = Az * qn;  a_lds[wv][384 + 64 + l] = Bz * qn;
    __syncthreads();

    int sp = species[node];
    float d0lo = 0.f, d0hi = 0.f, d1x = 0.f, d1y = 0.f, d1z = 0.f;
#pragma unroll 4
    for (int m = 0; m < 128; m++) {
        float am = a_lds[wv][m];
        d0lo += am * us2f(Wd0[(long)m * 128 + l]);
        d0hi += am * us2f(Wd0[(long)m * 128 + 64 + l]);
        float wd1 = us2f(Wd1[(long)m * 64 + l]);
        d1x += a_lds[wv][128 + m] * wd1;
        d1y += a_lds[wv][256 + m] * wd1;
        d1z += a_lds[wv][384 + m] * wd1;
    }
    float sc0lo = 0.f, sc0hi = 0.f, sc1x = 0.f, sc1y = 0.f, sc1z = 0.f;
#pragma unroll 4
    for (int m = 0; m < 64; m++) {
        float xm = us2f(x0[(long)node * 64 + m]);
        sc0lo += xm * us2f(Wsc0[((long)sp * 64 + m) * 128 + l]);
        sc0hi += xm * us2f(Wsc0[((long)sp * 64 + m) * 128 + 64 + l]);
        float w1m = us2f(Wsc1[((long)sp * 64 + m) * 64 + l]);
        sc1x += us2f(x1[(long)node * 192 + m * 3 + 0]) * w1m;
        sc1y += us2f(x1[(long)node * 192 + m * 3 + 1]) * w1m;
        sc1z += us2f(x1[(long)node * 192 + m * 3 + 2]) * w1m;
    }
    const float inv2 = 0.08838834764831845f;  // 1/sqrt(128)
    const float inv  = 0.125f;                // 1/sqrt(64)
    float f0lo = 0.5f * (d0lo * inv2 + sc0lo * inv);
    float f0hi = 0.5f * (d0hi * inv2 + sc0hi * inv);
    float scal = silu_f(f0lo);
    float gate = silu_f(f0hi);
    out[(long)node * 64 + l] = scal;
    long vb = (long)N64 + ((long)node * 64 + l) * 3;
    out[vb + 0] = 0.5f * (d1x * inv2 + sc1x * inv) * gate;
    out[vb + 1] = 0.5f * (d1y * inv2 + sc1y * inv) * gate;
    out[vb + 2] = 0.5f * (d1z * inv2 + sc1z * inv) * gate;
}

// ---------------- host launch --------------------------------------------------
extern "C" void kernel_launch(void* const* d_in, const int* in_sizes, int n_in,
                              void* d_out, int out_size, void* d_ws, size_t ws_size,
                              hipStream_t stream) {
    const int* senders   = (const int*)d_in[5];
    const int* receivers = (const int*)d_in[6];
    const int* species   = (const int*)d_in[7];
    float* out = (float*)d_out;

    char* ws = (char*)d_ws;
    size_t o = 0;
    auto alloc = [&](size_t bytes) { size_t p = o; o = (o + bytes + 255) & ~255UL; return p; };
    int* flag   = (int*)(ws + alloc(4));
    int* cnt    = (int*)(ws + alloc((size_t)NN * 4));
    int* offs   = (int*)(ws + alloc((size_t)(NN + 1) * 4));
    int* cursor = (int*)(ws + alloc((size_t)NN * 4));
    int* cpos   = (int*)(ws + alloc((size_t)NE * 4));
    int4* meta  = (int4*)(ws + alloc((size_t)NE * 16));
    u16* c_x0   = (u16*)(ws + alloc(SB0 * 2));
    u16* c_x1   = (u16*)(ws + alloc((SB1 - SB0) * 2));
    u16* c_ey0  = (u16*)(ws + alloc((SB2 - SB1) * 2));
    u16* c_ey1  = (u16*)(ws + alloc((SB3 - SB2) * 2));
    u16* c_re   = (u16*)(ws + alloc((SB4 - SB3) * 2));
    u16* c_Wup0 = (u16*)(ws + alloc((SB5 - SB4) * 2));
    u16* c_Wup1 = (u16*)(ws + alloc((SB6 - SB5) * 2));
    u16* c_Rw1  = (u16*)(ws + alloc((SB7 - SB6) * 2));
    u16* c_Rw2  = (u16*)(ws + alloc((SB8 - SB7) * 2));
    u16* c_Wd0  = (u16*)(ws + alloc((SB9 - SB8) * 2));
    u16* c_Wd1  = (u16*)(ws + alloc((SB10 - SB9) * 2));
    u16* c_Wsc0 = (u16*)(ws + alloc((SB11 - SB10) * 2));
    u16* c_Wsc1 = (u16*)(ws + alloc((SB12 - SB11) * 2));
    u16* h      = (u16*)(ws + alloc((size_t)NN * 256 * 2));   // [node][64][4]
    size_t fixed = o;                       // ~28.5 MB
    // wk chunk: [CAP][4 pass][64 ch] bf16; pick fewest chunks that fit ws_size
    int C = 128;
    for (int c = 2; c <= 128; c <<= 1) {
        size_t cap = (size_t)NE / c + 2048;
        if (fixed + cap * 512 <= ws_size) { C = c; break; }
    }
    int CAP = NE / C + 2048;
    u16* wk = (u16*)(ws + alloc((size_t)CAP * 512));
    int NNC = NN / C;

    k_sniff<<<1, 64, 0, stream>>>((const u16*)d_in[4], flag);
    k_convert<<<29058, 256, 0, stream>>>(d_in[0], d_in[1], d_in[2], d_in[3], d_in[4],
        d_in[8], d_in[9], d_in[10], d_in[11], d_in[12], d_in[13], d_in[14], d_in[15],
        flag, c_x0, c_x1, c_ey0, c_ey1, c_re,
        c_Wup0, c_Wup1, c_Rw1, c_Rw2, c_Wd0, c_Wd1, c_Wsc0, c_Wsc1);

    (void)hipMemsetAsync(cnt, 0, (size_t)NN * 4, stream);
    k_hist<<<NE / 256, 256, 0, stream>>>(receivers, cnt);
    k_scan<<<1, 256, 0, stream>>>(cnt, offs, cursor);
    k_scatter<<<NE / 256, 256, 0, stream>>>(receivers, senders, c_ey0, c_ey1,
                                            cursor, cpos, meta);

    k_up_gemm<<<dim3(NN / 256, 4), 256, 0, stream>>>(c_x0, c_x1, c_Wup0, c_Wup1, h);

    for (int c = 0; c < C; c++) {
        int n0 = c * NNC, n1 = n0 + NNC;
        k_radialE<<<NE / 64, 256, 0, stream>>>(c_re, c_Rw1, c_Rw2, cpos, offs,
                                               wk, n0, n1, CAP);
        k_node<<<NNC / 4, 256, 0, stream>>>(offs, wk, meta, h, c_x0, c_x1, species,
                                            c_Wd0, c_Wd1, c_Wsc0, c_Wsc1, out, n0, CAP);
    }
}

// Round 11
// 355.748 us; speedup vs baseline: 1.9847x; 1.0979x over previous
//
#include <hip/hip_runtime.h>

#define NN 16384          // nodes
#define NE 262144         // edges
#define N64 (NN * 64)

typedef unsigned short u16;
typedef __attribute__((ext_vector_type(8))) short short8;
typedef __attribute__((ext_vector_type(4))) float f32x4;

__device__ __forceinline__ float us2f(u16 u) {
    union { unsigned int i; float f; } v; v.i = ((unsigned int)u) << 16; return v.f;
}
__device__ __forceinline__ u16 f2us(float x) {   // f32 -> bf16 bits, RNE
    union { float f; unsigned int i; } u; u.f = x;
    unsigned int r = u.i + 0x7FFF + ((u.i >> 16) & 1);
    return (u16)(r >> 16);
}
__device__ __forceinline__ float silu_f(float x) { return x / (1.0f + __expf(-x)); }
__device__ __forceinline__ float ldf(const void* p, long i, int f) {
    return f ? ((const float*)p)[i] : us2f(((const u16*)p)[i]);
}

// ---------------- dtype sniff (drives only k_convert) --------------------------
__global__ void k_sniff(const u16* __restrict__ re, int* __restrict__ flag) {
    int t = threadIdx.x;
    int hit = (re[t] >= 0x4000) ? 1 : 0;
    unsigned long long b = __ballot(hit);
    if (t == 0) *flag = (__popcll(b) >= 4) ? 1 : 0;   // 1 => f32 inputs
}

// ---------------- convert all float tensors to bf16 + x1 transpose + hist ------
#define SB0 1048576L
#define SB1 4194304L
#define SB2 4456448L
#define SB3 5242880L
#define SB4 7340032L
#define SB5 7344128L
#define SB6 7348224L
#define SB7 7348736L
#define SB8 7365120L
#define SB9 7381504L
#define SB10 7389696L
#define SB11 7422464L
#define SB12 7438848L   // total; /256 = 29058 blocks

__global__ void k_convert(const void* x0, const void* x1, const void* ey0, const void* ey1,
                          const void* re, const void* Wup0, const void* Wup1, const void* Rw1,
                          const void* Rw2, const void* Wd0, const void* Wd1, const void* Wsc0,
                          const void* Wsc1, const int* __restrict__ flag,
                          const int* __restrict__ recv, int* __restrict__ cnt,
                          u16* c_x0, u16* x1T, u16* c_ey0, u16* c_ey1, u16* c_re,
                          u16* c_Wup0, u16* c_Wup1, u16* c_Rw1, u16* c_Rw2,
                          u16* c_Wd0, u16* c_Wd1, u16* c_Wsc0, u16* c_Wsc1) {
    long i = (long)blockIdx.x * 256 + threadIdx.x;
    int f = *flag;
    if (i < NE) atomicAdd(&cnt[recv[i]], 1);          // fused histogram
    if (i < SB0)       { c_x0[i]          = f2us(ldf(x0, i, f)); }
    else if (i < SB1)  {
        long j = i - SB0;
        int n = (int)(j / 192); int r = (int)(j % 192); int m = r / 3; int c = r % 3;
        x1T[(long)c * N64 + (long)n * 64 + m] = f2us(ldf(x1, j, f));
    }
    else if (i < SB2)  { c_ey0[i - SB1]   = f2us(ldf(ey0, i - SB1, f)); }
    else if (i < SB3)  { c_ey1[i - SB2]   = f2us(ldf(ey1, i - SB2, f)); }
    else if (i < SB4)  { c_re[i - SB3]    = f2us(ldf(re, i - SB3, f)); }
    else if (i < SB5)  { c_Wup0[i - SB4]  = f2us(ldf(Wup0, i - SB4, f)); }
    else if (i < SB6)  { c_Wup1[i - SB5]  = f2us(ldf(Wup1, i - SB5, f)); }
    else if (i < SB7)  { c_Rw1[i - SB6]   = f2us(ldf(Rw1, i - SB6, f)); }
    else if (i < SB8)  { c_Rw2[i - SB7]   = f2us(ldf(Rw2, i - SB7, f)); }
    else if (i < SB9)  { c_Wd0[i - SB8]   = f2us(ldf(Wd0, i - SB8, f)); }
    else if (i < SB10) { c_Wd1[i - SB9]   = f2us(ldf(Wd1, i - SB9, f)); }
    else if (i < SB11) { c_Wsc0[i - SB10] = f2us(ldf(Wsc0, i - SB10, f)); }
    else               { c_Wsc1[i - SB11] = f2us(ldf(Wsc1, i - SB11, f)); }
}

// ---------------- CSR scan + scatter -------------------------------------------
__global__ void k_scan(const int* __restrict__ cnt, int* __restrict__ offs,
                       int* __restrict__ cursor) {
    __shared__ int sd[256];
    int t = threadIdx.x;
    int base = t * 64;
    const int4* c4 = (const int4*)cnt;
    int loc[64];
#pragma unroll
    for (int i = 0; i < 16; i++) {
        int4 v = c4[t * 16 + i];
        loc[i * 4 + 0] = v.x; loc[i * 4 + 1] = v.y; loc[i * 4 + 2] = v.z; loc[i * 4 + 3] = v.w;
    }
    int sum = 0;
#pragma unroll
    for (int i = 0; i < 64; i++) sum += loc[i];
    sd[t] = sum; __syncthreads();
    for (int off = 1; off < 256; off <<= 1) {
        int v = (t >= off) ? sd[t - off] : 0;
        __syncthreads();
        sd[t] += v;
        __syncthreads();
    }
    int run = sd[t] - sum;
    for (int i = 0; i < 64; i++) {
        offs[base + i] = run; cursor[base + i] = run;
        run += loc[i];
    }
    if (t == 255) offs[NN] = run;
}

__global__ void k_scatter(const int* __restrict__ recv, const int* __restrict__ senders,
                          const u16* __restrict__ ey0, const u16* __restrict__ ey1,
                          int* __restrict__ cursor,
                          int* __restrict__ cpos, int4* __restrict__ meta) {
    int e = blockIdx.x * 256 + threadIdx.x;
    int p = atomicAdd(&cursor[recv[e]], 1);
    cpos[e] = p;
    unsigned y0  = ey0[e];
    unsigned y1x = ey1[(long)e * 3 + 0];
    unsigned y1y = ey1[(long)e * 3 + 1];
    unsigned y1z = ey1[(long)e * 3 + 2];
    int4 m;
    m.x = senders[e];
    m.y = (int)(y0 | (y1x << 16));
    m.z = (int)(y1y | (y1z << 16));
    m.w = e;
    meta[p] = m;
}

// ---------------- linear_up: h[node][64ch][4comp] interleaved bf16 --------------
__global__ void k_up_gemm(const u16* __restrict__ x0, const u16* __restrict__ x1T,
                          const u16* __restrict__ Wup0, const u16* __restrict__ Wup1,
                          u16* __restrict__ h) {
    int inst = blockIdx.y;
    int wv = threadIdx.x >> 6, lane = threadIdx.x & 63;
    int lhi = lane >> 4, llo = lane & 15;
    int mb = blockIdx.x * 256 + wv * 64;
    const u16* B = (inst == 0) ? Wup0 : Wup1;
    const u16* A = (inst == 0) ? x0 : (x1T + (long)(inst - 1) * N64);

    short8 bfr[4][2];
#pragma unroll
    for (int t = 0; t < 4; t++)
#pragma unroll
        for (int s = 0; s < 2; s++)
#pragma unroll
            for (int j = 0; j < 8; j++)
                bfr[t][s][j] = (short)B[(long)(s * 32 + lhi * 8 + j) * 64 + t * 16 + llo];

    f32x4 acc[4][4];
#pragma unroll
    for (int i = 0; i < 4; i++)
#pragma unroll
        for (int t = 0; t < 4; t++) acc[i][t] = 0.0f;

#pragma unroll
    for (int s = 0; s < 2; s++) {
        short8 af[4];
#pragma unroll
        for (int i = 0; i < 4; i++)
            af[i] = *reinterpret_cast<const short8*>(A + (long)(mb + i * 16 + llo) * 64 + s * 32 + lhi * 8);
#pragma unroll
        for (int i = 0; i < 4; i++)
#pragma unroll
            for (int t = 0; t < 4; t++)
                acc[i][t] = __builtin_amdgcn_mfma_f32_16x16x32_bf16(af[i], bfr[t][s], acc[i][t], 0, 0, 0);
    }
#pragma unroll
    for (int i = 0; i < 4; i++)
#pragma unroll
        for (int t = 0; t < 4; t++)
#pragma unroll
            for (int r = 0; r < 4; r++)
                h[(long)(mb + i * 16 + lhi * 4 + r) * 256 + (t * 16 + llo) * 4 + inst] =
                    f2us(acc[i][t][r] * 0.125f);
}

// ---------------- radial MLP: dense edge order, scatter full CSR records --------
#define RROW 272
__global__ void k_radialE(const u16* __restrict__ re, const u16* __restrict__ Rw1,
                          const u16* __restrict__ Rw2, const int* __restrict__ cpos,
                          const int* __restrict__ offs,
                          u16* __restrict__ wkc, int n0, int n1, int cap) {
    __shared__ u16 hid_s[64][72];
    __shared__ u16 w_lds[64 * RROW];
    int tid = threadIdx.x;
    int wv = tid >> 6, lane = tid & 63, lhi = lane >> 4, llo = lane & 15;
    int e0 = blockIdx.x * 64;
    int p0 = offs[n0];
    int p1 = offs[n1];
    if (p1 > p0 + cap) p1 = p0 + cap;

    {
        int el = tid >> 2;
        int jb = (tid & 3) * 16;
        int e = e0 + el;
        short8 r8 = *reinterpret_cast<const short8*>(re + (long)e * 8);
        float rr[8];
#pragma unroll
        for (int r = 0; r < 8; r++) rr[r] = us2f((u16)r8[r]);
        float hv[16];
#pragma unroll
        for (int q = 0; q < 2; q++) {
            short8 w8 = *reinterpret_cast<const short8*>(Rw1 + jb + q * 8);
#pragma unroll
            for (int j = 0; j < 8; j++) hv[q * 8 + j] = rr[0] * us2f((u16)w8[j]);
        }
#pragma unroll
        for (int r = 1; r < 8; r++) {
#pragma unroll
            for (int q = 0; q < 2; q++) {
                short8 w8 = *reinterpret_cast<const short8*>(Rw1 + (long)r * 64 + jb + q * 8);
#pragma unroll
                for (int j = 0; j < 8; j++) hv[q * 8 + j] += rr[r] * us2f((u16)w8[j]);
            }
        }
#pragma unroll
        for (int q = 0; q < 4; q++) {
            ushort4 pk;
            pk.x = f2us(silu_f(hv[q * 4 + 0] * 0.35355339059327373f));
            pk.y = f2us(silu_f(hv[q * 4 + 1] * 0.35355339059327373f));
            pk.z = f2us(silu_f(hv[q * 4 + 2] * 0.35355339059327373f));
            pk.w = f2us(silu_f(hv[q * 4 + 3] * 0.35355339059327373f));
            *reinterpret_cast<ushort4*>(&hid_s[el][jb + q * 4]) = pk;
        }
    }
    __syncthreads();
    {
        short8 bfr[4][2];
#pragma unroll
        for (int t = 0; t < 4; t++)
#pragma unroll
            for (int s = 0; s < 2; s++)
#pragma unroll
                for (int j = 0; j < 8; j++)
                    bfr[t][s][j] = (short)Rw2[(long)(s * 32 + lhi * 8 + j) * 256 + wv * 64 + t * 16 + llo];
        f32x4 acc[4][4];
#pragma unroll
        for (int i = 0; i < 4; i++)
#pragma unroll
            for (int t = 0; t < 4; t++) acc[i][t] = 0.0f;
#pragma unroll
        for (int s = 0; s < 2; s++) {
            short8 af[4];
#pragma unroll
            for (int i = 0; i < 4; i++)
                af[i] = *reinterpret_cast<const short8*>(&hid_s[i * 16 + llo][s * 32 + lhi * 8]);
#pragma unroll
            for (int i = 0; i < 4; i++)
#pragma unroll
                for (int t = 0; t < 4; t++)
                    acc[i][t] = __builtin_amdgcn_mfma_f32_16x16x32_bf16(af[i], bfr[t][s], acc[i][t], 0, 0, 0);
        }
#pragma unroll
        for (int i = 0; i < 4; i++)
#pragma unroll
            for (int t = 0; t < 4; t++)
#pragma unroll
                for (int r = 0; r < 4; r++)
                    w_lds[(i * 16 + lhi * 4 + r) * RROW + wv * 64 + t * 16 + llo] =
                        f2us(acc[i][t][r] * 0.125f);
    }
    __syncthreads();
    {
        int i = tid >> 2, q = tid & 3;
        int cp = cpos[e0 + i];
        if (cp >= p0 && cp < p1) {
            const u16* src = &w_lds[i * RROW + q * 64];
            u16* dst = wkc + (long)(cp - p0) * 256 + q * 64;
#pragma unroll
            for (int j = 0; j < 8; j++)
                *reinterpret_cast<f32x4*>(dst + j * 8) = *reinterpret_cast<const f32x4*>(src + j * 8);
        }
    }
}

// ---------------- gather only: per-node message accumulation -> abuf bf16 -------
__global__ void k_gather(const int* __restrict__ offs, const u16* __restrict__ wkc,
                         const int4* __restrict__ meta, const u16* __restrict__ h,
                         u16* __restrict__ abuf, int n0, int cap) {
    int wv = threadIdx.x >> 6, l = threadIdx.x & 63;
    int node = n0 + blockIdx.x * 4 + wv;
    int cbase = offs[n0];
    int beg = offs[node] - cbase, end = offs[node + 1] - cbase;
    if (beg > cap) beg = cap;
    if (end > cap) end = cap;

    float A0a = 0.f, A0b = 0.f;
    float Ax = 0.f, Ay = 0.f, Az = 0.f;
    float Bx = 0.f, By = 0.f, Bz = 0.f;

    int idx = beg;
    for (; idx + 2 <= end; idx += 2) {
        int4 m0 = meta[cbase + idx];
        int4 m1 = meta[cbase + idx + 1];
        const u16* wr0 = wkc + (long)idx * 256;
        const u16* wr1 = wkc + (long)(idx + 1) * 256;
        float w00 = us2f(wr0[l]),       w01 = us2f(wr0[64 + l]);
        float w02 = us2f(wr0[128 + l]), w03 = us2f(wr0[192 + l]);
        float w10 = us2f(wr1[l]),       w11 = us2f(wr1[64 + l]);
        float w12 = us2f(wr1[128 + l]), w13 = us2f(wr1[192 + l]);
        ushort4 h0v = *reinterpret_cast<const ushort4*>(h + (long)m0.x * 256 + l * 4);
        ushort4 h1v = *reinterpret_cast<const ushort4*>(h + (long)m1.x * 256 + l * 4);
        {
            float y0  = us2f((u16)((unsigned)m0.y & 0xffff));
            float y1x = us2f((u16)((unsigned)m0.y >> 16));
            float y1y = us2f((u16)((unsigned)m0.z & 0xffff));
            float y1z = us2f((u16)((unsigned)m0.z >> 16));
            float s0 = us2f(h0v.x), s1x = us2f(h0v.y), s1y = us2f(h0v.z), s1z = us2f(h0v.w);
            A0a += w00 * s0 * y0;
            A0b += w01 * (s1x * y1x + s1y * y1y + s1z * y1z);
            Ax += w02 * s0 * y1x; Ay += w02 * s0 * y1y; Az += w02 * s0 * y1z;
            Bx += w03 * s1x * y0; By += w03 * s1y * y0; Bz += w03 * s1z * y0;
        }
        {
            float y0  = us2f((u16)((unsigned)m1.y & 0xffff));
            float y1x = us2f((u16)((unsigned)m1.y >> 16));
            float y1y = us2f((u16)((unsigned)m1.z & 0xffff));
            float y1z = us2f((u16)((unsigned)m1.z >> 16));
            float s0 = us2f(h1v.x), s1x = us2f(h1v.y), s1y = us2f(h1v.z), s1z = us2f(h1v.w);
            A0a += w10 * s0 * y0;
            A0b += w11 * (s1x * y1x + s1y * y1y + s1z * y1z);
            Ax += w12 * s0 * y1x; Ay += w12 * s0 * y1y; Az += w12 * s0 * y1z;
            Bx += w13 * s1x * y0; By += w13 * s1y * y0; Bz += w13 * s1z * y0;
        }
    }
    if (idx < end) {
        int4 m0 = meta[cbase + idx];
        const u16* wr0 = wkc + (long)idx * 256;
        float w00 = us2f(wr0[l]),       w01 = us2f(wr0[64 + l]);
        float w02 = us2f(wr0[128 + l]), w03 = us2f(wr0[192 + l]);
        ushort4 h0v = *reinterpret_cast<const ushort4*>(h + (long)m0.x * 256 + l * 4);
        float y0  = us2f((u16)((unsigned)m0.y & 0xffff));
        float y1x = us2f((u16)((unsigned)m0.y >> 16));
        float y1y = us2f((u16)((unsigned)m0.z & 0xffff));
        float y1z = us2f((u16)((unsigned)m0.z >> 16));
        float s0 = us2f(h0v.x), s1x = us2f(h0v.y), s1y = us2f(h0v.z), s1z = us2f(h0v.w);
        A0a += w00 * s0 * y0;
        A0b += w01 * (s1x * y1x + s1y * y1y + s1z * y1z);
        Ax += w02 * s0 * y1x; Ay += w02 * s0 * y1y; Az += w02 * s0 * y1z;
        Bx += w03 * s1x * y0; By += w03 * s1y * y0; Bz += w03 * s1z * y0;
    }

    const float qn = 0.25f;                 // 1/sqrt(avg_neigh)
    const float rs3 = 0.57735026918962576f; // 1/sqrt(3)
    u16* ab = abuf + (long)node * 512;      // [a0(128) | a1x(128) | a1y | a1z]
    ab[l]        = f2us(A0a * qn);
    ab[64 + l]   = f2us(A0b * qn * rs3);
    ab[128 + l]  = f2us(Ax * qn);  ab[192 + l] = f2us(Bx * qn);
    ab[256 + l]  = f2us(Ay * qn);  ab[320 + l] = f2us(By * qn);
    ab[384 + l]  = f2us(Az * qn);  ab[448 + l] = f2us(Bz * qn);
}

// ---------------- linear_down + species sc + gate (MFMA) ------------------------
// Block = 64 nodes, 5 waves: wave g = output group {scal, gate, vx, vy, vz}.
// d-GEMM K=128 from abuf; sc computed for all 4 species and row-selected.
__global__ void k_down(const u16* __restrict__ abuf, const u16* __restrict__ x0,
                       const u16* __restrict__ x1T, const int* __restrict__ species,
                       const u16* __restrict__ Wd0, const u16* __restrict__ Wd1,
                       const u16* __restrict__ Wsc0, const u16* __restrict__ Wsc1,
                       float* __restrict__ out) {
    __shared__ float gate_s[64][65];
    __shared__ int sp_s[64];
    int tid = threadIdx.x;
    int g = tid >> 6;
    int lane = tid & 63, lhi = lane >> 4, llo = lane & 15;
    int node0 = blockIdx.x * 64;
    if (tid < 64) sp_s[tid] = species[node0 + tid];
    __syncthreads();

    const u16* Ad; const u16* Bd; int ldb, bcol;
    const u16* As; const u16* Bs; int lsb, sstr;
    if (g <= 1) { Ad = abuf; Bd = Wd0; ldb = 128; bcol = g * 64; As = x0; Bs = Wsc0; lsb = 128; sstr = 8192; }
    else        { Ad = abuf + (g - 1) * 128; Bd = Wd1; ldb = 64; bcol = 0;
                  As = x1T + (long)(g - 2) * N64; Bs = Wsc1; lsb = 64; sstr = 4096; }

    short8 bd[4][4];   // [coltile][kstep]
#pragma unroll
    for (int ct = 0; ct < 4; ct++)
#pragma unroll
        for (int ks = 0; ks < 4; ks++)
#pragma unroll
            for (int j = 0; j < 8; j++)
                bd[ct][ks][j] = (short)Bd[(long)(ks * 32 + lhi * 8 + j) * ldb + bcol + ct * 16 + llo];

    const float inv2 = 0.08838834764831845f;  // 1/sqrt(128)
    const float inv  = 0.125f;                // 1/sqrt(64)
    f32x4 fv[4][4];

#pragma unroll
    for (int rt = 0; rt < 4; rt++) {
        int arow = node0 + rt * 16 + llo;
        f32x4 accd[4];
#pragma unroll
        for (int ct = 0; ct < 4; ct++) accd[ct] = 0.0f;
#pragma unroll
        for (int ks = 0; ks < 4; ks++) {
            short8 a = *reinterpret_cast<const short8*>(Ad + (long)arow * 512 + ks * 32 + lhi * 8);
#pragma unroll
            for (int ct = 0; ct < 4; ct++)
                accd[ct] = __builtin_amdgcn_mfma_f32_16x16x32_bf16(a, bd[ct][ks], accd[ct], 0, 0, 0);
        }
        int spv[4];
#pragma unroll
        for (int r = 0; r < 4; r++) spv[r] = sp_s[rt * 16 + lhi * 4 + r];
        f32x4 res[4];
#pragma unroll
        for (int ct = 0; ct < 4; ct++) res[ct] = 0.0f;
        for (int s = 0; s < 4; s++) {
            short8 bs[4][2];
#pragma unroll
            for (int ct = 0; ct < 4; ct++)
#pragma unroll
                for (int ks = 0; ks < 2; ks++)
#pragma unroll
                    for (int j = 0; j < 8; j++)
                        bs[ct][ks][j] = (short)Bs[(long)s * sstr + (long)(ks * 32 + lhi * 8 + j) * lsb + bcol + ct * 16 + llo];
            f32x4 accs[4];
#pragma unroll
            for (int ct = 0; ct < 4; ct++) accs[ct] = 0.0f;
#pragma unroll
            for (int ks = 0; ks < 2; ks++) {
                short8 a2 = *reinterpret_cast<const short8*>(As + (long)arow * 64 + ks * 32 + lhi * 8);
#pragma unroll
                for (int ct = 0; ct < 4; ct++)
                    accs[ct] = __builtin_amdgcn_mfma_f32_16x16x32_bf16(a2, bs[ct][ks], accs[ct], 0, 0, 0);
            }
#pragma unroll
            for (int ct = 0; ct < 4; ct++)
#pragma unroll
                for (int r = 0; r < 4; r++)
                    if (spv[r] == s) res[ct][r] = accs[ct][r];
        }
#pragma unroll
        for (int ct = 0; ct < 4; ct++)
#pragma unroll
            for (int r = 0; r < 4; r++)
                fv[rt][ct][r] = 0.5f * (accd[ct][r] * inv2 + res[ct][r] * inv);
        if (g == 0) {
#pragma unroll
            for (int ct = 0; ct < 4; ct++)
#pragma unroll
                for (int r = 0; r < 4; r++)
                    out[(long)(node0 + rt * 16 + lhi * 4 + r) * 64 + ct * 16 + llo] = silu_f(fv[rt][ct][r]);
        } else if (g == 1) {
#pragma unroll
            for (int ct = 0; ct < 4; ct++)
#pragma unroll
                for (int r = 0; r < 4; r++)
                    gate_s[rt * 16 + lhi * 4 + r][ct * 16 + llo] = silu_f(fv[rt][ct][r]);
        }
    }
    __syncthreads();
    if (g >= 2) {
        int c = g - 2;
#pragma unroll
        for (int rt = 0; rt < 4; rt++)
#pragma unroll
            for (int ct = 0; ct < 4; ct++)
#pragma unroll
                for (int r = 0; r < 4; r++) {
                    int row = rt * 16 + lhi * 4 + r;
                    int col = ct * 16 + llo;
                    float v = fv[rt][ct][r] * gate_s[row][col];
                    out[(long)N64 + ((long)(node0 + row) * 64 + col) * 3 + c] = v;
                }
    }
}

// ---------------- host launch --------------------------------------------------
extern "C" void kernel_launch(void* const* d_in, const int* in_sizes, int n_in,
                              void* d_out, int out_size, void* d_ws, size_t ws_size,
                              hipStream_t stream) {
    const int* senders   = (const int*)d_in[5];
    const int* receivers = (const int*)d_in[6];
    const int* species   = (const int*)d_in[7];
    float* out = (float*)d_out;

    char* ws = (char*)d_ws;
    size_t o = 0;
    auto alloc = [&](size_t bytes) { size_t p = o; o = (o + bytes + 255) & ~255UL; return p; };
    int* flag   = (int*)(ws + alloc(4));
    int* cnt    = (int*)(ws + alloc((size_t)NN * 4));
    int* offs   = (int*)(ws + alloc((size_t)(NN + 1) * 4));
    int* cursor = (int*)(ws + alloc((size_t)NN * 4));
    int* cpos   = (int*)(ws + alloc((size_t)NE * 4));
    int4* meta  = (int4*)(ws + alloc((size_t)NE * 16));
    u16* c_x0   = (u16*)(ws + alloc(SB0 * 2));
    u16* x1T    = (u16*)(ws + alloc((size_t)3 * N64 * 2));
    u16* c_ey0  = (u16*)(ws + alloc((SB2 - SB1) * 2));
    u16* c_ey1  = (u16*)(ws + alloc((SB3 - SB2) * 2));
    u16* c_re   = (u16*)(ws + alloc((SB4 - SB3) * 2));
    u16* c_Wup0 = (u16*)(ws + alloc((SB5 - SB4) * 2));
    u16* c_Wup1 = (u16*)(ws + alloc((SB6 - SB5) * 2));
    u16* c_Rw1  = (u16*)(ws + alloc((SB7 - SB6) * 2));
    u16* c_Rw2  = (u16*)(ws + alloc((SB8 - SB7) * 2));
    u16* c_Wd0  = (u16*)(ws + alloc((SB9 - SB8) * 2));
    u16* c_Wd1  = (u16*)(ws + alloc((SB10 - SB9) * 2));
    u16* c_Wsc0 = (u16*)(ws + alloc((SB11 - SB10) * 2));
    u16* c_Wsc1 = (u16*)(ws + alloc((SB12 - SB11) * 2));
    u16* h      = (u16*)(ws + alloc((size_t)NN * 256 * 2));   // [node][64][4]
    u16* abuf   = (u16*)(ws + alloc((size_t)NN * 512 * 2));   // [node][512]
    size_t fixed = o;                       // ~45 MB
    int C = 128;
    for (int c = 1; c <= 128; c <<= 1) {
        size_t cap = (size_t)NE / c + 2048;
        if (fixed + cap * 512 <= ws_size) { C = c; break; }
    }
    int CAP = NE / C + 2048;
    u16* wk = (u16*)(ws + alloc((size_t)CAP * 512));
    int NNC = NN / C;

    k_sniff<<<1, 64, 0, stream>>>((const u16*)d_in[4], flag);
    (void)hipMemsetAsync(cnt, 0, (size_t)NN * 4, stream);
    k_convert<<<29058, 256, 0, stream>>>(d_in[0], d_in[1], d_in[2], d_in[3], d_in[4],
        d_in[8], d_in[9], d_in[10], d_in[11], d_in[12], d_in[13], d_in[14], d_in[15],
        flag, receivers, cnt,
        c_x0, x1T, c_ey0, c_ey1, c_re,
        c_Wup0, c_Wup1, c_Rw1, c_Rw2, c_Wd0, c_Wd1, c_Wsc0, c_Wsc1);
    k_scan<<<1, 256, 0, stream>>>(cnt, offs, cursor);
    k_scatter<<<NE / 256, 256, 0, stream>>>(receivers, senders, c_ey0, c_ey1,
                                            cursor, cpos, meta);

    k_up_gemm<<<dim3(NN / 256, 4), 256, 0, stream>>>(c_x0, x1T, c_Wup0, c_Wup1, h);

    for (int c = 0; c < C; c++) {
        int n0 = c * NNC, n1 = n0 + NNC;
        k_radialE<<<NE / 64, 256, 0, stream>>>(c_re, c_Rw1, c_Rw2, cpos, offs,
                                               wk, n0, n1, CAP);
        k_gather<<<NNC / 4, 256, 0, stream>>>(offs, wk, meta, h, abuf, n0, CAP);
    }

    k_down<<<NN / 64, 320, 0, stream>>>((const u16*)abuf, c_x0, x1T, species,
                                        c_Wd0, c_Wd1, c_Wsc0, c_Wsc1, out);
}